// Round 1
// baseline (3244.327 us; speedup 1.0000x reference)
//
#include <hip/hip_runtime.h>
#include <hip/hip_bf16.h>

#define NEGS 0.2f

// ---------------- degree / norm ----------------
__global__ void k_deg(const int* __restrict__ dst, float* deg, int E) {
    int e = blockIdx.x * blockDim.x + threadIdx.x;
    if (e < E) atomicAdd(&deg[dst[e]], 1.0f);
}

__global__ void k_norm(float* x, int N) {
    int i = blockIdx.x * blockDim.x + threadIdx.x;
    if (i < N) x[i] = 1.0f / sqrtf(fmaxf(x[i], 1.0f));
}

// ---------------- GEMM: C[N,M] = A[N,K] @ B[K,M] (+bias) ----------------
// tile 64 rows x 32 cols, K-chunks of 16, 256 threads, 4x2 per thread
__global__ __launch_bounds__(256)
void k_gemm(const float* __restrict__ A, const float* __restrict__ B,
            const float* __restrict__ bias, float* __restrict__ C,
            int Nrows, int K, int M) {
    __shared__ float As[16][68];   // transposed: As[kk][r], stride 68 (272B, 16B-aligned, 2-way max)
    __shared__ float Bs[16][32];   // Bs[kk][c]
    const int r0 = blockIdx.x * 64;
    const int c0 = blockIdx.y * 32;
    const int tid = threadIdx.x;
    const int tr = (tid / 16) * 4;   // 0..60
    const int tc = (tid % 16) * 2;   // 0..30
    float acc[4][2] = {};
    for (int k0 = 0; k0 < K; k0 += 16) {
        #pragma unroll
        for (int i = tid; i < 64 * 16; i += 256) {
            int r = i / 16, kk = i % 16;
            float v = 0.0f;
            if (r0 + r < Nrows && k0 + kk < K) v = A[(size_t)(r0 + r) * K + k0 + kk];
            As[kk][r] = v;
        }
        #pragma unroll
        for (int i = tid; i < 16 * 32; i += 256) {
            int kk = i / 32, c = i % 32;
            float v = 0.0f;
            if (k0 + kk < K && c0 + c < M) v = B[(size_t)(k0 + kk) * M + c0 + c];
            Bs[kk][c] = v;
        }
        __syncthreads();
        #pragma unroll
        for (int kk = 0; kk < 16; kk++) {
            float a0 = As[kk][tr], a1 = As[kk][tr + 1], a2 = As[kk][tr + 2], a3 = As[kk][tr + 3];
            float b0 = Bs[kk][tc], b1 = Bs[kk][tc + 1];
            acc[0][0] += a0 * b0; acc[0][1] += a0 * b1;
            acc[1][0] += a1 * b0; acc[1][1] += a1 * b1;
            acc[2][0] += a2 * b0; acc[2][1] += a2 * b1;
            acc[3][0] += a3 * b0; acc[3][1] += a3 * b1;
        }
        __syncthreads();
    }
    #pragma unroll
    for (int j = 0; j < 4; j++) {
        int r = r0 + tr + j;
        if (r >= Nrows) continue;
        #pragma unroll
        for (int c = 0; c < 2; c++) {
            int cc = c0 + tc + c;
            if (cc >= M) continue;
            float v = acc[j][c];
            if (bias) v += bias[cc];
            C[(size_t)r * M + cc] = v;
        }
    }
}

// ---------------- attention pieces ----------------
__global__ void k_elr(const float* __restrict__ feat, const float* __restrict__ al,
                      const float* __restrict__ ar, float* __restrict__ el,
                      float* __restrict__ er, int N, int H, int D) {
    int i = blockIdx.x * blockDim.x + threadIdx.x;  // n*H + h
    if (i >= N * H) return;
    int h = i % H;
    const float* f = feat + (size_t)i * D;
    const float* a = al + h * D;
    const float* b = ar + h * D;
    float sl = 0.0f, sr = 0.0f;
    for (int d = 0; d < D; d++) { float v = f[d]; sl += v * a[d]; sr += v * b[d]; }
    el[i] = sl; er[i] = sr;
}

__device__ inline unsigned fkey(float x) {
    unsigned b = __float_as_uint(x);
    return (b & 0x80000000u) ? ~b : (b | 0x80000000u);
}
__device__ inline float funkey(unsigned u) {
    return __uint_as_float((u & 0x80000000u) ? (u & 0x7fffffffu) : ~u);
}

__global__ void k_elogit(const int* __restrict__ src, const int* __restrict__ dst,
                         const float* __restrict__ el, const float* __restrict__ er,
                         float* __restrict__ e, unsigned* __restrict__ emax, int E, int H) {
    int i = blockIdx.x * blockDim.x + threadIdx.x;  // e*H + h
    if (i >= E * H) return;
    int ed = i / H, h = i - ed * H;
    float x = el[src[ed] * H + h] + er[dst[ed] * H + h];
    x = (x > 0.0f) ? x : NEGS * x;
    e[i] = x;
    atomicMax(&emax[dst[ed] * H + h], fkey(x));
}

__global__ void k_esoft(const int* __restrict__ dst, float* __restrict__ e,
                        const unsigned* __restrict__ emax, float* __restrict__ denom,
                        int E, int H) {
    int i = blockIdx.x * blockDim.x + threadIdx.x;
    if (i >= E * H) return;
    int ed = i / H, h = i - ed * H;
    int dh = dst[ed] * H + h;
    float w = __expf(e[i] - funkey(emax[dh]));
    e[i] = w;
    atomicAdd(&denom[dh], w);
}

__global__ void k_aggregate(const int* __restrict__ src, const int* __restrict__ dst,
                            const float* __restrict__ feat, const float* __restrict__ ew,
                            const float* __restrict__ denom, float* __restrict__ out,
                            int E, int H, int D) {
    int i = blockIdx.x * blockDim.x + threadIdx.x;  // e*(H*D) + h*D + d
    int HD = H * D;
    if (i >= E * HD) return;
    int ed = i / HD, hd = i - ed * HD;
    int h = hd / D;
    int s = src[ed], t = dst[ed];
    float alpha = ew[ed * H + h] / denom[t * H + h];
    atomicAdd(&out[(size_t)t * HD + hd], feat[(size_t)s * HD + hd] * alpha);
}

// ---------------- residual scatter / elementwise ----------------
__global__ void k_scatter(const int* __restrict__ src, const int* __restrict__ dst,
                          const float* __restrict__ v, float* __restrict__ out, int E, int M) {
    int i = blockIdx.x * blockDim.x + threadIdx.x;
    if (i >= E * M) return;
    int ed = i / M, c = i - ed * M;
    atomicAdd(&out[(size_t)dst[ed] * M + c], v[(size_t)src[ed] * M + c]);
}

__global__ void k_rowscale(float* __restrict__ x, const float* __restrict__ s, int N, int M) {
    int i = blockIdx.x * blockDim.x + threadIdx.x;
    if (i < N * M) x[i] *= s[i / M];
}

__global__ void k_relu(const float* __restrict__ in, float* __restrict__ out, int n) {
    int i = blockIdx.x * blockDim.x + threadIdx.x;
    if (i < n) out[i] = fmaxf(in[i], 0.0f);
}

__global__ void k_add_relu(const float* __restrict__ a, const float* __restrict__ b,
                           float* __restrict__ out, int n) {
    int i = blockIdx.x * blockDim.x + threadIdx.x;
    if (i < n) out[i] = fmaxf(a[i] + b[i], 0.0f);
}

// ---------------- launch ----------------
extern "C" void kernel_launch(void* const* d_in, const int* in_sizes, int n_in,
                              void* d_out, int out_size, void* d_ws, size_t ws_size,
                              hipStream_t stream) {
    const float* features = (const float*)d_in[0];
    const int*   src      = (const int*)d_in[1];
    const int*   dst      = (const int*)d_in[2];
    const float* W0   = (const float*)d_in[3];
    const float* al0  = (const float*)d_in[4];
    const float* ar0  = (const float*)d_in[5];
    const float* W1   = (const float*)d_in[6];
    const float* al1  = (const float*)d_in[7];
    const float* ar1  = (const float*)d_in[8];
    const float* W2   = (const float*)d_in[9];
    const float* al2  = (const float*)d_in[10];
    const float* ar2  = (const float*)d_in[11];
    const float* Wout = (const float*)d_in[12];
    const float* alout= (const float*)d_in[13];
    const float* arout= (const float*)d_in[14];
    const float* Wraw = (const float*)d_in[15];
    const float* braw = (const float*)d_in[16];

    const int IN = 300, H = 5, D = 32, HD = 160, OUT = 10;
    const int N = in_sizes[0] / IN;   // 50000
    const int E = in_sizes[1];        // 800000

    float* p = (float*)d_ws;
    float* norm = p;                 p += N;
    float* res  = p;                 p += (size_t)N * HD;
    float* gat  = p;                 p += (size_t)N * HD;   // rawn, then GAT accumulator
    float* hbuf = p;                 p += (size_t)N * HD;
    float* feat = p;                 p += (size_t)N * HD;
    float* el   = p;                 p += N * H;
    float* er   = p;                 p += N * H;
    unsigned* emax = (unsigned*)p;   p += N * H;
    float* denom = p;                p += N * H;
    float* ebuf  = p;                p += (size_t)E * H;
    float* out = (float*)d_out;

    auto cdiv = [](long long a, long long b) { return (int)((a + b - 1) / b); };

    // 1. degree -> norm
    hipMemsetAsync(norm, 0, N * sizeof(float), stream);
    k_deg<<<cdiv(E, 256), 256, 0, stream>>>(dst, norm, E);
    k_norm<<<cdiv(N, 256), 256, 0, stream>>>(norm, N);

    // 2. rawn = (features @ Wraw + braw) * norm   (into gat buffer)
    k_gemm<<<dim3(cdiv(N, 64), cdiv(HD, 32)), 256, 0, stream>>>(features, Wraw, braw, gat, N, IN, HD);
    k_rowscale<<<cdiv((long long)N * HD, 256), 256, 0, stream>>>(gat, norm, N, HD);

    // 3. res = norm * scatter_sum(rawn[src] -> dst)   (loop-invariant, used by layers 1 & 2)
    hipMemsetAsync(res, 0, (size_t)N * HD * sizeof(float), stream);
    k_scatter<<<cdiv((long long)E * HD, 256), 256, 0, stream>>>(src, dst, gat, res, E, HD);
    k_rowscale<<<cdiv((long long)N * HD, 256), 256, 0, stream>>>(res, norm, N, HD);

    // 4. three GAT layers
    const float* x = features; int K = IN;
    const float* Ws[3]  = {W0, W1, W2};
    const float* als[3] = {al0, al1, al2};
    const float* ars[3] = {ar0, ar1, ar2};
    for (int L = 0; L < 3; L++) {
        k_gemm<<<dim3(cdiv(N, 64), cdiv(HD, 32)), 256, 0, stream>>>(x, Ws[L], nullptr, feat, N, K, HD);
        k_elr<<<cdiv((long long)N * H, 256), 256, 0, stream>>>(feat, als[L], ars[L], el, er, N, H, D);
        hipMemsetAsync(emax, 0, (size_t)N * H * 4, stream);
        k_elogit<<<cdiv((long long)E * H, 256), 256, 0, stream>>>(src, dst, el, er, ebuf, emax, E, H);
        hipMemsetAsync(denom, 0, (size_t)N * H * 4, stream);
        k_esoft<<<cdiv((long long)E * H, 256), 256, 0, stream>>>(dst, ebuf, emax, denom, E, H);
        hipMemsetAsync(gat, 0, (size_t)N * HD * 4, stream);
        k_aggregate<<<cdiv((long long)E * HD, 256), 256, 0, stream>>>(src, dst, feat, ebuf, denom, gat, E, H, D);
        if (L == 0)
            k_relu<<<cdiv((long long)N * HD, 256), 256, 0, stream>>>(gat, hbuf, N * HD);
        else
            k_add_relu<<<cdiv((long long)N * HD, 256), 256, 0, stream>>>(gat, res, hbuf, N * HD);
        x = hbuf; K = HD;
    }

    // 5. output GAT (H=1, D=OUT), mean over 1 head == identity; write straight to d_out
    k_gemm<<<dim3(cdiv(N, 64), 1), 256, 0, stream>>>(hbuf, Wout, nullptr, feat, N, HD, OUT);
    k_elr<<<cdiv(N, 256), 256, 0, stream>>>(feat, alout, arout, el, er, N, 1, OUT);
    hipMemsetAsync(emax, 0, (size_t)N * 4, stream);
    k_elogit<<<cdiv(E, 256), 256, 0, stream>>>(src, dst, el, er, ebuf, emax, E, 1);
    hipMemsetAsync(denom, 0, (size_t)N * 4, stream);
    k_esoft<<<cdiv(E, 256), 256, 0, stream>>>(dst, ebuf, emax, denom, E, 1);
    hipMemsetAsync(out, 0, (size_t)N * OUT * 4, stream);
    k_aggregate<<<cdiv((long long)E * OUT, 256), 256, 0, stream>>>(src, dst, feat, ebuf, denom, out, E, 1, OUT);
}

// Round 3
// 1801.883 us; speedup vs baseline: 1.8005x; 1.8005x over previous
//
#include <hip/hip_runtime.h>
#include <hip/hip_bf16.h>

#define NEGS 0.2f

// ---------------- CSR build ----------------
__global__ void k_degi(const int* __restrict__ dst, int* __restrict__ deg, int E) {
    int e = blockIdx.x * blockDim.x + threadIdx.x;
    if (e < E) atomicAdd(&deg[dst[e]], 1);
}

// single-block scan over N (<= 1024*chunk), also emits norm = rsqrt(max(deg,1))
__global__ __launch_bounds__(1024)
void k_scan(const int* __restrict__ deg, int* __restrict__ rowptr,
            float* __restrict__ norm, int N) {
    __shared__ int ssum[1024];
    int t = threadIdx.x;
    int chunk = (N + 1023) >> 10;
    int b = min(t * chunk, N), e = min(b + chunk, N);
    int s = 0;
    for (int i = b; i < e; ++i) s += deg[i];
    ssum[t] = s;
    __syncthreads();
    for (int off = 1; off < 1024; off <<= 1) {
        int v = (t >= off) ? ssum[t - off] : 0;
        __syncthreads();
        ssum[t] += v;
        __syncthreads();
    }
    int run = (t == 0) ? 0 : ssum[t - 1];
    for (int i = b; i < e; ++i) { rowptr[i] = run; run += deg[i]; }
    if (t == 0) rowptr[N] = ssum[1023];
    for (int i = b; i < e; ++i) norm[i] = rsqrtf(fmaxf((float)deg[i], 1.0f));
}

__global__ void k_fill(const int* __restrict__ src, const int* __restrict__ dst,
                       const int* __restrict__ rowptr, int* __restrict__ cnt,
                       int* __restrict__ csr_src, int E) {
    int e = blockIdx.x * blockDim.x + threadIdx.x;
    if (e >= E) return;
    int d = dst[e];
    int pos = rowptr[d] + atomicAdd(&cnt[d], 1);
    csr_src[pos] = src[e];
}

// ---------------- GEMM: C[N,M] = A[N,K] @ B[K,M] (+bias) ----------------
__global__ __launch_bounds__(256)
void k_gemm(const float* __restrict__ A, const float* __restrict__ B,
            const float* __restrict__ bias, float* __restrict__ C,
            int Nrows, int K, int M) {
    __shared__ float As[16][68];
    __shared__ float Bs[16][32];
    const int r0 = blockIdx.x * 64;
    const int c0 = blockIdx.y * 32;
    const int tid = threadIdx.x;
    const int tr = (tid / 16) * 4;
    const int tc = (tid % 16) * 2;
    float acc[4][2] = {};
    for (int k0 = 0; k0 < K; k0 += 16) {
        #pragma unroll
        for (int i = tid; i < 64 * 16; i += 256) {
            int r = i / 16, kk = i % 16;
            float v = 0.0f;
            if (r0 + r < Nrows && k0 + kk < K) v = A[(size_t)(r0 + r) * K + k0 + kk];
            As[kk][r] = v;
        }
        #pragma unroll
        for (int i = tid; i < 16 * 32; i += 256) {
            int kk = i / 32, c = i % 32;
            float v = 0.0f;
            if (k0 + kk < K && c0 + c < M) v = B[(size_t)(k0 + kk) * M + c0 + c];
            Bs[kk][c] = v;
        }
        __syncthreads();
        #pragma unroll
        for (int kk = 0; kk < 16; kk++) {
            float a0 = As[kk][tr], a1 = As[kk][tr + 1], a2 = As[kk][tr + 2], a3 = As[kk][tr + 3];
            float b0 = Bs[kk][tc], b1 = Bs[kk][tc + 1];
            acc[0][0] += a0 * b0; acc[0][1] += a0 * b1;
            acc[1][0] += a1 * b0; acc[1][1] += a1 * b1;
            acc[2][0] += a2 * b0; acc[2][1] += a2 * b1;
            acc[3][0] += a3 * b0; acc[3][1] += a3 * b1;
        }
        __syncthreads();
    }
    #pragma unroll
    for (int j = 0; j < 4; j++) {
        int r = r0 + tr + j;
        if (r >= Nrows) continue;
        #pragma unroll
        for (int c = 0; c < 2; c++) {
            int cc = c0 + tc + c;
            if (cc >= M) continue;
            float v = acc[j][c];
            if (bias) v += bias[cc];
            C[(size_t)r * M + cc] = v;
        }
    }
}

// ---------------- attention logits el/er ----------------
__global__ void k_elr(const float* __restrict__ feat, const float* __restrict__ al,
                      const float* __restrict__ ar, float* __restrict__ el,
                      float* __restrict__ er, int N, int H, int D) {
    int i = blockIdx.x * blockDim.x + threadIdx.x;  // n*H + h
    if (i >= N * H) return;
    int h = i % H;
    const float* f = feat + (size_t)i * D;
    const float* a = al + h * D;
    const float* b = ar + h * D;
    float sl = 0.0f, sr = 0.0f;
    for (int d = 0; d < D; d++) { float v = f[d]; sl += v * a[d]; sr += v * b[d]; }
    el[i] = sl; er[i] = sr;
}

// ---------------- fused GAT: softmax + weighted gather, one wave per node ----
// relu_mode: 0 = none, 1 = relu, 2 = add res then relu
template<int H, int D>
__global__ __launch_bounds__(64)
void k_gat_fused(const int* __restrict__ rowptr, const int* __restrict__ csr_src,
                 const float* __restrict__ el, const float* __restrict__ er,
                 const float* __restrict__ feat, const float* __restrict__ res,
                 float* __restrict__ out, int relu_mode) {
    constexpr int HD = H * D;
    constexpr int SLOTS = (HD + 63) / 64;
    const int n = blockIdx.x;
    const int lane = threadIdx.x;
    const int beg = rowptr[n], end = rowptr[n + 1];

    float erh[H];
    #pragma unroll
    for (int h = 0; h < H; ++h) erh[h] = er[n * H + h];

    // pass 1: per-head max over incoming edges (recompute logits; nothing stored)
    float m[H];
    #pragma unroll
    for (int h = 0; h < H; ++h) m[h] = -1e30f;
    for (int j = beg + lane; j < end; j += 64) {
        int s = csr_src[j];
        #pragma unroll
        for (int h = 0; h < H; ++h) {
            float x = el[s * H + h] + erh[h];
            x = (x > 0.0f) ? x : (NEGS * x);
            m[h] = fmaxf(m[h], x);
        }
    }
    #pragma unroll
    for (int h = 0; h < H; ++h)
        for (int off = 32; off; off >>= 1) m[h] = fmaxf(m[h], __shfl_xor(m[h], off, 64));

    // pass 2: per-head denom
    float ssum[H];
    #pragma unroll
    for (int h = 0; h < H; ++h) ssum[h] = 0.0f;
    for (int j = beg + lane; j < end; j += 64) {
        int s = csr_src[j];
        #pragma unroll
        for (int h = 0; h < H; ++h) {
            float x = el[s * H + h] + erh[h];
            x = (x > 0.0f) ? x : (NEGS * x);
            ssum[h] += __expf(x - m[h]);
        }
    }
    #pragma unroll
    for (int h = 0; h < H; ++h) {
        for (int off = 32; off; off >>= 1) ssum[h] += __shfl_xor(ssum[h], off, 64);
        ssum[h] = (ssum[h] > 0.0f) ? 1.0f / ssum[h] : 0.0f;
    }

    // pass 3: weighted gather-accumulate, 64-edge chunks via LDS
    __shared__ float s_alpha[64 * H];
    __shared__ int   s_src[64];
    float acc[SLOTS];
    #pragma unroll
    for (int r = 0; r < SLOTS; ++r) acc[r] = 0.0f;

    for (int chunk = beg; chunk < end; chunk += 64) {
        int j = chunk + lane;
        if (j < end) {
            int s = csr_src[j];
            s_src[lane] = s;
            #pragma unroll
            for (int h = 0; h < H; ++h) {
                float x = el[s * H + h] + erh[h];
                x = (x > 0.0f) ? x : (NEGS * x);
                s_alpha[lane * H + h] = __expf(x - m[h]) * ssum[h];
            }
        }
        __syncthreads();
        int cnt = min(64, end - chunk);
        for (int t = 0; t < cnt; ++t) {
            const float* fr = feat + (size_t)s_src[t] * HD;
            #pragma unroll
            for (int r = 0; r < SLOTS; ++r) {
                int hd = r * 64 + lane;
                if (hd < HD)
                    acc[r] += s_alpha[t * H + hd / D] * fr[hd];
            }
        }
        __syncthreads();
    }

    // epilogue: fold residual + relu, coalesced write
    #pragma unroll
    for (int r = 0; r < SLOTS; ++r) {
        int hd = r * 64 + lane;
        if (hd < HD) {
            float v = acc[r];
            if (relu_mode == 2) v += res[(size_t)n * HD + hd];
            if (relu_mode) v = fmaxf(v, 0.0f);
            out[(size_t)n * HD + hd] = v;
        }
    }
}

// ---------------- residual: res = norm_dst * sum_in(rawn[src]) ----------------
__global__ void k_res_gather(const int* __restrict__ rowptr, const int* __restrict__ csr_src,
                             const float* __restrict__ rawn, const float* __restrict__ norm,
                             float* __restrict__ res, int N, int M) {
    int i = blockIdx.x * blockDim.x + threadIdx.x;
    if (i >= N * M) return;
    int n = i / M, hd = i - n * M;
    int beg = rowptr[n], end = rowptr[n + 1];
    float acc = 0.0f;
    for (int j = beg; j < end; ++j)
        acc += rawn[(size_t)csr_src[j] * M + hd];
    res[i] = acc * norm[n];
}

__global__ void k_rowscale(float* __restrict__ x, const float* __restrict__ s, int N, int M) {
    int i = blockIdx.x * blockDim.x + threadIdx.x;
    if (i < N * M) x[i] *= s[i / M];
}

// ---------------- launch ----------------
extern "C" void kernel_launch(void* const* d_in, const int* in_sizes, int n_in,
                              void* d_out, int out_size, void* d_ws, size_t ws_size,
                              hipStream_t stream) {
    const float* features = (const float*)d_in[0];
    const int*   src      = (const int*)d_in[1];
    const int*   dst      = (const int*)d_in[2];
    const float* W0   = (const float*)d_in[3];
    const float* al0  = (const float*)d_in[4];
    const float* ar0  = (const float*)d_in[5];
    const float* W1   = (const float*)d_in[6];
    const float* al1  = (const float*)d_in[7];
    const float* ar1  = (const float*)d_in[8];
    const float* W2   = (const float*)d_in[9];
    const float* al2  = (const float*)d_in[10];
    const float* ar2  = (const float*)d_in[11];
    const float* Wout = (const float*)d_in[12];
    const float* alout= (const float*)d_in[13];
    const float* arout= (const float*)d_in[14];
    const float* Wraw = (const float*)d_in[15];
    const float* braw = (const float*)d_in[16];

    const int IN = 300, H = 5, D = 32, HD = 160, OUT = 10;
    const int N = in_sizes[0] / IN;   // 50000
    const int E = in_sizes[1];        // 800000

    char* w = (char*)d_ws;
    auto take = [&](size_t bytes) { char* r = w; w += (bytes + 255) & ~size_t(255); return r; };
    int*   deg     = (int*)  take((size_t)N * 4);
    int*   cnt     = (int*)  take((size_t)N * 4);
    int*   rowptr  = (int*)  take((size_t)(N + 1) * 4);
    int*   csr_src = (int*)  take((size_t)E * 4);
    float* norm    = (float*)take((size_t)N * 4);
    float* res     = (float*)take((size_t)N * HD * 4);
    float* rawn    = (float*)take((size_t)N * HD * 4);
    float* hbuf    = (float*)take((size_t)N * HD * 4);
    float* feat    = (float*)take((size_t)N * HD * 4);
    float* el      = (float*)take((size_t)N * H * 4);
    float* er      = (float*)take((size_t)N * H * 4);
    float* out = (float*)d_out;

    auto cdiv = [](long long a, long long b) { return (int)((a + b - 1) / b); };

    // 1. CSR build + norm
    hipMemsetAsync(deg, 0, (size_t)N * 4, stream);
    hipMemsetAsync(cnt, 0, (size_t)N * 4, stream);
    k_degi<<<cdiv(E, 256), 256, 0, stream>>>(dst, deg, E);
    k_scan<<<1, 1024, 0, stream>>>(deg, rowptr, norm, N);
    k_fill<<<cdiv(E, 256), 256, 0, stream>>>(src, dst, rowptr, cnt, csr_src, E);

    // 2. rawn = (features @ Wraw + braw) * norm
    k_gemm<<<dim3(cdiv(N, 64), cdiv(HD, 32)), 256, 0, stream>>>(features, Wraw, braw, rawn, N, IN, HD);
    k_rowscale<<<cdiv((long long)N * HD, 256), 256, 0, stream>>>(rawn, norm, N, HD);

    // 3. res = norm * gather_sum(rawn[src])   (loop-invariant)
    k_res_gather<<<cdiv((long long)N * HD, 256), 256, 0, stream>>>(rowptr, csr_src, rawn, norm, res, N, HD);

    // 4. three GAT layers (fused softmax+aggregate, relu/residual folded)
    const float* x = features; int K = IN;
    const float* Ws[3]  = {W0, W1, W2};
    const float* als[3] = {al0, al1, al2};
    const float* ars[3] = {ar0, ar1, ar2};
    for (int L = 0; L < 3; L++) {
        k_gemm<<<dim3(cdiv(N, 64), cdiv(HD, 32)), 256, 0, stream>>>(x, Ws[L], nullptr, feat, N, K, HD);
        k_elr<<<cdiv((long long)N * H, 256), 256, 0, stream>>>(feat, als[L], ars[L], el, er, N, H, D);
        k_gat_fused<5, 32><<<N, 64, 0, stream>>>(rowptr, csr_src, el, er, feat, res, hbuf,
                                                 (L == 0) ? 1 : 2);
        x = hbuf; K = HD;
    }

    // 5. output GAT (H=1, D=OUT); mean over 1 head == identity; write d_out
    k_gemm<<<dim3(cdiv(N, 64), 1), 256, 0, stream>>>(hbuf, Wout, nullptr, feat, N, HD, OUT);
    k_elr<<<cdiv(N, 256), 256, 0, stream>>>(feat, alout, arout, el, er, N, 1, OUT);
    k_gat_fused<1, 10><<<N, 64, 0, stream>>>(rowptr, csr_src, el, er, feat, nullptr, out, 0);
}

// Round 4
// 1699.616 us; speedup vs baseline: 1.9089x; 1.0602x over previous
//
#include <hip/hip_runtime.h>
#include <hip/hip_bf16.h>

#define NEGS 0.2f

// ---------------- CSR build ----------------
__global__ void k_degi(const int* __restrict__ dst, int* __restrict__ deg, int E) {
    int e = blockIdx.x * blockDim.x + threadIdx.x;
    if (e < E) atomicAdd(&deg[dst[e]], 1);
}

__global__ __launch_bounds__(1024)
void k_scan(const int* __restrict__ deg, int* __restrict__ rowptr,
            float* __restrict__ norm, int N) {
    __shared__ int ssum[1024];
    int t = threadIdx.x;
    int chunk = (N + 1023) >> 10;
    int b = min(t * chunk, N), e = min(b + chunk, N);
    int s = 0;
    for (int i = b; i < e; ++i) s += deg[i];
    ssum[t] = s;
    __syncthreads();
    for (int off = 1; off < 1024; off <<= 1) {
        int v = (t >= off) ? ssum[t - off] : 0;
        __syncthreads();
        ssum[t] += v;
        __syncthreads();
    }
    int run = (t == 0) ? 0 : ssum[t - 1];
    for (int i = b; i < e; ++i) { rowptr[i] = run; run += deg[i]; }
    if (t == 0) rowptr[N] = ssum[1023];
    for (int i = b; i < e; ++i) norm[i] = rsqrtf(fmaxf((float)deg[i], 1.0f));
}

__global__ void k_fill(const int* __restrict__ src, const int* __restrict__ dst,
                       const int* __restrict__ rowptr, int* __restrict__ cnt,
                       int* __restrict__ csr_src, int E) {
    int e = blockIdx.x * blockDim.x + threadIdx.x;
    if (e >= E) return;
    int d = dst[e];
    int pos = rowptr[d] + atomicAdd(&cnt[d], 1);
    csr_src[pos] = src[e];
}

// ---------------- wide GEMM: C[N,M] = A[N,K] @ B[K,M], full-width M tile ----
// 64 rows x (NC*32) cols per block, 256 threads, 8 rows x NC cols per thread.
// A fetched exactly once. Optional bias (per-col) and rowscale (per-row).
template<int NC>
__global__ __launch_bounds__(256)
void k_gemm_wide(const float* __restrict__ A, const float* __restrict__ B,
                 const float* __restrict__ bias, const float* __restrict__ rowscale,
                 float* __restrict__ C, int Nrows, int K, int M) {
    __shared__ __align__(16) float As[16][68];       // transposed A tile, 68-stride
    __shared__ float Bs[16][NC * 32];
    const int r0 = blockIdx.x * 64;
    const int tid = threadIdx.x;
    const int tx = tid & 31;          // col lane
    const int ty = tid >> 5;          // row group 0..7
    float acc[8][NC];
    #pragma unroll
    for (int r = 0; r < 8; ++r)
        #pragma unroll
        for (int c = 0; c < NC; ++c) acc[r][c] = 0.0f;

    for (int k0 = 0; k0 < K; k0 += 16) {
        // stage A: 64 rows x 16 k, one float4 of k per thread
        {
            int r = tid >> 2;               // 0..63
            int kk = (tid & 3) * 4;         // 0,4,8,12
            int row = r0 + r;
            float4 v = make_float4(0.f, 0.f, 0.f, 0.f);
            if (row < Nrows) {
                int kb = k0 + kk;
                if (kb + 3 < K) {
                    v = *reinterpret_cast<const float4*>(&A[(size_t)row * K + kb]);
                } else {
                    float tmp[4] = {0.f, 0.f, 0.f, 0.f};
                    #pragma unroll
                    for (int j = 0; j < 4; ++j)
                        if (kb + j < K) tmp[j] = A[(size_t)row * K + kb + j];
                    v = make_float4(tmp[0], tmp[1], tmp[2], tmp[3]);
                }
            }
            As[kk + 0][r] = v.x; As[kk + 1][r] = v.y;
            As[kk + 2][r] = v.z; As[kk + 3][r] = v.w;
        }
        // stage B: 16 x NC*32 (guarded)
        for (int i = tid; i < 16 * NC * 32; i += 256) {
            int kk = i / (NC * 32), c = i % (NC * 32);
            float v = 0.0f;
            if (k0 + kk < K && c < M) v = B[(size_t)(k0 + kk) * M + c];
            Bs[kk][c] = v;
        }
        __syncthreads();
        #pragma unroll
        for (int kk = 0; kk < 16; ++kk) {
            float4 a0 = *reinterpret_cast<const float4*>(&As[kk][ty * 8]);
            float4 a1 = *reinterpret_cast<const float4*>(&As[kk][ty * 8 + 4]);
            float av[8] = {a0.x, a0.y, a0.z, a0.w, a1.x, a1.y, a1.z, a1.w};
            float bv[NC];
            #pragma unroll
            for (int c = 0; c < NC; ++c) bv[c] = Bs[kk][tx + 32 * c];
            #pragma unroll
            for (int r = 0; r < 8; ++r)
                #pragma unroll
                for (int c = 0; c < NC; ++c) acc[r][c] += av[r] * bv[c];
        }
        __syncthreads();
    }

    #pragma unroll
    for (int r = 0; r < 8; ++r) {
        int row = r0 + ty * 8 + r;
        if (row >= Nrows) continue;
        float sc = rowscale ? rowscale[row] : 1.0f;
        #pragma unroll
        for (int c = 0; c < NC; ++c) {
            int col = tx + 32 * c;
            if (col < M) {
                float v = acc[r][c];
                if (bias) v += bias[col];
                C[(size_t)row * M + col] = v * sc;
            }
        }
    }
}

// ---------------- attention logits el/er ----------------
__global__ void k_elr32(const float* __restrict__ feat, const float* __restrict__ al,
                        const float* __restrict__ ar, float* __restrict__ el,
                        float* __restrict__ er, int N, int H) {
    int i = blockIdx.x * blockDim.x + threadIdx.x;  // n*H + h
    if (i >= N * H) return;
    int h = i % H;
    const float4* f = (const float4*)(feat + (size_t)i * 32);
    const float4* a = (const float4*)(al + h * 32);
    const float4* b = (const float4*)(ar + h * 32);
    float sl = 0.0f, sr = 0.0f;
    #pragma unroll
    for (int d = 0; d < 8; d++) {
        float4 v = f[d], x = a[d], y = b[d];
        sl += v.x * x.x + v.y * x.y + v.z * x.z + v.w * x.w;
        sr += v.x * y.x + v.y * y.y + v.z * y.z + v.w * y.w;
    }
    el[i] = sl; er[i] = sr;
}

__global__ void k_elr_gen(const float* __restrict__ feat, const float* __restrict__ al,
                          const float* __restrict__ ar, float* __restrict__ el,
                          float* __restrict__ er, int N, int H, int D) {
    int i = blockIdx.x * blockDim.x + threadIdx.x;
    if (i >= N * H) return;
    int h = i % H;
    const float* f = feat + (size_t)i * D;
    const float* a = al + h * D;
    const float* b = ar + h * D;
    float sl = 0.0f, sr = 0.0f;
    for (int d = 0; d < D; d++) { float v = f[d]; sl += v * a[d]; sr += v * b[d]; }
    el[i] = sl; er[i] = sr;
}

// ---------------- fused GAT: softmax + weighted gather, one wave per node ----
template<int H, int D>
__global__ __launch_bounds__(64)
void k_gat_fused(const int* __restrict__ rowptr, const int* __restrict__ csr_src,
                 const float* __restrict__ el, const float* __restrict__ er,
                 const float* __restrict__ feat, const float* __restrict__ res,
                 float* __restrict__ out, int relu_mode) {
    constexpr int HD = H * D;
    constexpr int SLOTS = (HD + 63) / 64;
    const int n = blockIdx.x;
    const int lane = threadIdx.x;
    const int beg = rowptr[n], end = rowptr[n + 1];

    float erh[H];
    #pragma unroll
    for (int h = 0; h < H; ++h) erh[h] = er[n * H + h];

    float m[H];
    #pragma unroll
    for (int h = 0; h < H; ++h) m[h] = -1e30f;
    for (int j = beg + lane; j < end; j += 64) {
        int s = csr_src[j];
        #pragma unroll
        for (int h = 0; h < H; ++h) {
            float x = el[s * H + h] + erh[h];
            x = (x > 0.0f) ? x : (NEGS * x);
            m[h] = fmaxf(m[h], x);
        }
    }
    #pragma unroll
    for (int h = 0; h < H; ++h)
        for (int off = 32; off; off >>= 1) m[h] = fmaxf(m[h], __shfl_xor(m[h], off, 64));

    float ssum[H];
    #pragma unroll
    for (int h = 0; h < H; ++h) ssum[h] = 0.0f;
    for (int j = beg + lane; j < end; j += 64) {
        int s = csr_src[j];
        #pragma unroll
        for (int h = 0; h < H; ++h) {
            float x = el[s * H + h] + erh[h];
            x = (x > 0.0f) ? x : (NEGS * x);
            ssum[h] += __expf(x - m[h]);
        }
    }
    #pragma unroll
    for (int h = 0; h < H; ++h) {
        for (int off = 32; off; off >>= 1) ssum[h] += __shfl_xor(ssum[h], off, 64);
        ssum[h] = (ssum[h] > 0.0f) ? 1.0f / ssum[h] : 0.0f;
    }

    __shared__ float s_alpha[64 * H];
    __shared__ int   s_src[64];
    float acc[SLOTS];
    #pragma unroll
    for (int r = 0; r < SLOTS; ++r) acc[r] = 0.0f;

    for (int chunk = beg; chunk < end; chunk += 64) {
        int j = chunk + lane;
        if (j < end) {
            int s = csr_src[j];
            s_src[lane] = s;
            #pragma unroll
            for (int h = 0; h < H; ++h) {
                float x = el[s * H + h] + erh[h];
                x = (x > 0.0f) ? x : (NEGS * x);
                s_alpha[lane * H + h] = __expf(x - m[h]) * ssum[h];
            }
        }
        __syncthreads();
        int cnt = min(64, end - chunk);
        for (int t = 0; t < cnt; ++t) {
            const float* fr = feat + (size_t)s_src[t] * HD;
            #pragma unroll
            for (int r = 0; r < SLOTS; ++r) {
                int hd = r * 64 + lane;
                if (hd < HD)
                    acc[r] += s_alpha[t * H + hd / D] * fr[hd];
            }
        }
        __syncthreads();
    }

    #pragma unroll
    for (int r = 0; r < SLOTS; ++r) {
        int hd = r * 64 + lane;
        if (hd < HD) {
            float v = acc[r];
            if (relu_mode == 2) v += res[(size_t)n * HD + hd];
            if (relu_mode) v = fmaxf(v, 0.0f);
            out[(size_t)n * HD + hd] = v;
        }
    }
}

// ---------------- residual: res = norm_dst * sum_in(rawn[src]) ----------------
__global__ void k_res_gather(const int* __restrict__ rowptr, const int* __restrict__ csr_src,
                             const float* __restrict__ rawn, const float* __restrict__ norm,
                             float* __restrict__ res, int N, int M) {
    int i = blockIdx.x * blockDim.x + threadIdx.x;
    if (i >= N * M) return;
    int n = i / M, hd = i - n * M;
    int beg = rowptr[n], end = rowptr[n + 1];
    float acc = 0.0f;
    for (int j = beg; j < end; ++j)
        acc += rawn[(size_t)csr_src[j] * M + hd];
    res[i] = acc * norm[n];
}

// ---------------- launch ----------------
extern "C" void kernel_launch(void* const* d_in, const int* in_sizes, int n_in,
                              void* d_out, int out_size, void* d_ws, size_t ws_size,
                              hipStream_t stream) {
    const float* features = (const float*)d_in[0];
    const int*   src      = (const int*)d_in[1];
    const int*   dst      = (const int*)d_in[2];
    const float* W0   = (const float*)d_in[3];
    const float* al0  = (const float*)d_in[4];
    const float* ar0  = (const float*)d_in[5];
    const float* W1   = (const float*)d_in[6];
    const float* al1  = (const float*)d_in[7];
    const float* ar1  = (const float*)d_in[8];
    const float* W2   = (const float*)d_in[9];
    const float* al2  = (const float*)d_in[10];
    const float* ar2  = (const float*)d_in[11];
    const float* Wout = (const float*)d_in[12];
    const float* alout= (const float*)d_in[13];
    const float* arout= (const float*)d_in[14];
    const float* Wraw = (const float*)d_in[15];
    const float* braw = (const float*)d_in[16];

    const int IN = 300, H = 5, D = 32, HD = 160, OUT = 10;
    const int N = in_sizes[0] / IN;   // 50000
    const int E = in_sizes[1];        // 800000

    char* w = (char*)d_ws;
    auto take = [&](size_t bytes) { char* r = w; w += (bytes + 255) & ~size_t(255); return r; };
    int*   deg     = (int*)  take((size_t)N * 4);
    int*   cnt     = (int*)  take((size_t)N * 4);
    int*   rowptr  = (int*)  take((size_t)(N + 1) * 4);
    int*   csr_src = (int*)  take((size_t)E * 4);
    float* norm    = (float*)take((size_t)N * 4);
    float* res     = (float*)take((size_t)N * HD * 4);
    float* rawn    = (float*)take((size_t)N * HD * 4);
    float* hbuf    = (float*)take((size_t)N * HD * 4);
    float* feat    = (float*)take((size_t)N * HD * 4);
    float* el      = (float*)take((size_t)N * H * 4);
    float* er      = (float*)take((size_t)N * H * 4);
    float* out = (float*)d_out;

    auto cdiv = [](long long a, long long b) { return (int)((a + b - 1) / b); };

    // 1. CSR build + norm
    hipMemsetAsync(deg, 0, (size_t)N * 4, stream);
    hipMemsetAsync(cnt, 0, (size_t)N * 4, stream);
    k_degi<<<cdiv(E, 256), 256, 0, stream>>>(dst, deg, E);
    k_scan<<<1, 1024, 0, stream>>>(deg, rowptr, norm, N);
    k_fill<<<cdiv(E, 256), 256, 0, stream>>>(src, dst, rowptr, cnt, csr_src, E);

    // 2. rawn = (features @ Wraw + braw) * norm   (norm folded into epilogue)
    k_gemm_wide<5><<<cdiv(N, 64), 256, 0, stream>>>(features, Wraw, braw, norm, rawn, N, IN, HD);

    // 3. res = norm * gather_sum(rawn[src])   (loop-invariant)
    k_res_gather<<<cdiv((long long)N * HD, 256), 256, 0, stream>>>(rowptr, csr_src, rawn, norm, res, N, HD);

    // 4. three GAT layers
    const float* x = features; int K = IN;
    const float* Ws[3]  = {W0, W1, W2};
    const float* als[3] = {al0, al1, al2};
    const float* ars[3] = {ar0, ar1, ar2};
    for (int L = 0; L < 3; L++) {
        k_gemm_wide<5><<<cdiv(N, 64), 256, 0, stream>>>(x, Ws[L], nullptr, nullptr, feat, N, K, HD);
        k_elr32<<<cdiv((long long)N * H, 256), 256, 0, stream>>>(feat, als[L], ars[L], el, er, N, H);
        k_gat_fused<5, 32><<<N, 64, 0, stream>>>(rowptr, csr_src, el, er, feat, res, hbuf,
                                                 (L == 0) ? 1 : 2);
        x = hbuf; K = HD;
    }

    // 5. output GAT (H=1, D=OUT); mean over 1 head == identity
    k_gemm_wide<1><<<cdiv(N, 64), 256, 0, stream>>>(hbuf, Wout, nullptr, nullptr, feat, N, HD, OUT);
    k_elr_gen<<<cdiv(N, 256), 256, 0, stream>>>(feat, alout, arout, el, er, N, 1, OUT);
    k_gat_fused<1, 10><<<N, 64, 0, stream>>>(rowptr, csr_src, el, er, feat, nullptr, out, 0);
}

// Round 5
// 1455.810 us; speedup vs baseline: 2.2285x; 1.1675x over previous
//
#include <hip/hip_runtime.h>
#include <hip/hip_bf16.h>

#define NEGS 0.2f

// ---------------- CSR build ----------------
__global__ void k_degi(const int* __restrict__ dst, int* __restrict__ deg, int E) {
    int e = blockIdx.x * blockDim.x + threadIdx.x;
    if (e < E) atomicAdd(&deg[dst[e]], 1);
}

__global__ __launch_bounds__(1024)
void k_scan(const int* __restrict__ deg, int* __restrict__ rowptr,
            float* __restrict__ norm, int N) {
    __shared__ int ssum[1024];
    int t = threadIdx.x;
    int chunk = (N + 1023) >> 10;
    int b = min(t * chunk, N), e = min(b + chunk, N);
    int s = 0;
    for (int i = b; i < e; ++i) s += deg[i];
    ssum[t] = s;
    __syncthreads();
    for (int off = 1; off < 1024; off <<= 1) {
        int v = (t >= off) ? ssum[t - off] : 0;
        __syncthreads();
        ssum[t] += v;
        __syncthreads();
    }
    int run = (t == 0) ? 0 : ssum[t - 1];
    for (int i = b; i < e; ++i) { rowptr[i] = run; run += deg[i]; }
    if (t == 0) rowptr[N] = ssum[1023];
    for (int i = b; i < e; ++i) norm[i] = rsqrtf(fmaxf((float)deg[i], 1.0f));
}

__global__ void k_fill(const int* __restrict__ src, const int* __restrict__ dst,
                       const int* __restrict__ rowptr, int* __restrict__ cnt,
                       int* __restrict__ csr_src, int E) {
    int e = blockIdx.x * blockDim.x + threadIdx.x;
    if (e >= E) return;
    int d = dst[e];
    int pos = rowptr[d] + atomicAdd(&cnt[d], 1);
    csr_src[pos] = src[e];
}

// ---------------- GEMM v2: C[N,160] = A[N,K] @ B[K,160] -----------------
// 32 rows x 160 cols per block, 256 threads (4 rows x 5 cols each),
// double-buffered LDS, one barrier per 16-k chunk. A fetched exactly once.
__global__ __launch_bounds__(256)
void k_gemm160(const float* __restrict__ A, const float* __restrict__ B,
               const float* __restrict__ bias, const float* __restrict__ rowscale,
               float* __restrict__ C, int Nrows, int K) {
    constexpr int M = 160;
    __shared__ __align__(16) float As[2][16][36];    // transposed, padded stride
    __shared__ __align__(16) float Bs[2][16][160];
    const int tid = threadIdx.x;
    const int tx = tid & 31, ty = tid >> 5;
    const int r0 = blockIdx.x * 32;
    const int nT = (K + 15) / 16;

    float4 a_reg;
    float4 b_reg[3];

    auto loadA = [&](int t) {
        a_reg = make_float4(0.f, 0.f, 0.f, 0.f);
        if (tid < 128) {
            int r = tid >> 2, kq = (tid & 3) * 4;
            int row = r0 + r, kb = t * 16 + kq;
            if (row < Nrows) {
                if (kb + 3 < K) {
                    a_reg = *reinterpret_cast<const float4*>(&A[(size_t)row * K + kb]);
                } else {
                    float tmp[4] = {0.f, 0.f, 0.f, 0.f};
                    #pragma unroll
                    for (int j = 0; j < 4; ++j)
                        if (kb + j < K) tmp[j] = A[(size_t)row * K + kb + j];
                    a_reg = make_float4(tmp[0], tmp[1], tmp[2], tmp[3]);
                }
            }
        }
    };
    auto loadB = [&](int t) {
        #pragma unroll
        for (int q = 0; q < 3; ++q) {
            b_reg[q] = make_float4(0.f, 0.f, 0.f, 0.f);
            int i = tid + q * 256;
            if (i < 640) {
                int kk = i / 40, c4 = (i % 40) * 4;
                int kb = t * 16 + kk;
                if (kb < K) b_reg[q] = *reinterpret_cast<const float4*>(&B[(size_t)kb * M + c4]);
            }
        }
    };
    auto storeA = [&](int buf) {
        if (tid < 128) {
            int r = tid >> 2, kq = (tid & 3) * 4;
            As[buf][kq + 0][r] = a_reg.x; As[buf][kq + 1][r] = a_reg.y;
            As[buf][kq + 2][r] = a_reg.z; As[buf][kq + 3][r] = a_reg.w;
        }
    };
    auto storeB = [&](int buf) {
        #pragma unroll
        for (int q = 0; q < 3; ++q) {
            int i = tid + q * 256;
            if (i < 640) {
                int kk = i / 40, c4 = (i % 40) * 4;
                *reinterpret_cast<float4*>(&Bs[buf][kk][c4]) = b_reg[q];
            }
        }
    };

    float acc[4][5] = {};
    loadA(0); loadB(0);
    storeA(0); storeB(0);
    __syncthreads();
    for (int t = 0; t < nT; ++t) {
        int cur = t & 1;
        if (t + 1 < nT) { loadA(t + 1); loadB(t + 1); }   // global->reg, hides under FMAs
        #pragma unroll
        for (int kk = 0; kk < 16; ++kk) {
            float4 av = *reinterpret_cast<const float4*>(&As[cur][kk][ty * 4]);
            float a4[4] = {av.x, av.y, av.z, av.w};
            float bv[5];
            #pragma unroll
            for (int c = 0; c < 5; ++c) bv[c] = Bs[cur][kk][tx + 32 * c];
            #pragma unroll
            for (int r = 0; r < 4; ++r)
                #pragma unroll
                for (int c = 0; c < 5; ++c) acc[r][c] += a4[r] * bv[c];
        }
        if (t + 1 < nT) { storeA(cur ^ 1); storeB(cur ^ 1); }
        __syncthreads();
    }
    #pragma unroll
    for (int r = 0; r < 4; ++r) {
        int row = r0 + ty * 4 + r;
        if (row >= Nrows) continue;
        float sc = rowscale ? rowscale[row] : 1.0f;
        #pragma unroll
        for (int c = 0; c < 5; ++c) {
            int col = tx + 32 * c;
            float v = acc[r][c];
            if (bias) v += bias[col];
            C[(size_t)row * M + col] = v * sc;
        }
    }
}

// ---------------- small GEMM for Wout: C[N,10] = A[N,160] @ B[160,10] ----
__global__ __launch_bounds__(256)
void k_gemv10(const float* __restrict__ A, const float* __restrict__ B,
              float* __restrict__ C, int Nrows, int K) {
    __shared__ float Bs[160 * 10];
    for (int i = threadIdx.x; i < K * 10; i += 256) Bs[i] = B[i];
    __syncthreads();
    int row = blockIdx.x * 256 + threadIdx.x;
    if (row >= Nrows) return;
    float acc[10] = {};
    const float4* a = reinterpret_cast<const float4*>(A + (size_t)row * K);
    for (int kq = 0; kq < K / 4; ++kq) {
        float4 v = a[kq];
        int k = kq * 4;
        #pragma unroll
        for (int j = 0; j < 10; ++j)
            acc[j] += v.x * Bs[(k + 0) * 10 + j] + v.y * Bs[(k + 1) * 10 + j]
                    + v.z * Bs[(k + 2) * 10 + j] + v.w * Bs[(k + 3) * 10 + j];
    }
    #pragma unroll
    for (int j = 0; j < 10; ++j) C[(size_t)row * 10 + j] = acc[j];
}

// ---------------- attention logits el/er ----------------
__global__ void k_elr32(const float* __restrict__ feat, const float* __restrict__ al,
                        const float* __restrict__ ar, float* __restrict__ el,
                        float* __restrict__ er, int N, int H) {
    int i = blockIdx.x * blockDim.x + threadIdx.x;  // n*H + h
    if (i >= N * H) return;
    int h = i % H;
    const float4* f = (const float4*)(feat + (size_t)i * 32);
    const float4* a = (const float4*)(al + h * 32);
    const float4* b = (const float4*)(ar + h * 32);
    float sl = 0.0f, sr = 0.0f;
    #pragma unroll
    for (int d = 0; d < 8; d++) {
        float4 v = f[d], x = a[d], y = b[d];
        sl += v.x * x.x + v.y * x.y + v.z * x.z + v.w * x.w;
        sr += v.x * y.x + v.y * y.y + v.z * y.z + v.w * y.w;
    }
    el[i] = sl; er[i] = sr;
}

__global__ void k_elr_gen(const float* __restrict__ feat, const float* __restrict__ al,
                          const float* __restrict__ ar, float* __restrict__ el,
                          float* __restrict__ er, int N, int H, int D) {
    int i = blockIdx.x * blockDim.x + threadIdx.x;
    if (i >= N * H) return;
    int h = i % H;
    const float* f = feat + (size_t)i * D;
    const float* a = al + h * D;
    const float* b = ar + h * D;
    float sl = 0.0f, sr = 0.0f;
    for (int d = 0; d < D; d++) { float v = f[d]; sl += v * a[d]; sr += v * b[d]; }
    el[i] = sl; er[i] = sr;
}

// ---------------- fused GAT: softmax + weighted gather, one wave per node ----
template<int H, int D>
__global__ __launch_bounds__(64)
void k_gat_fused(const int* __restrict__ rowptr, const int* __restrict__ csr_src,
                 const float* __restrict__ el, const float* __restrict__ er,
                 const float* __restrict__ feat, const float* __restrict__ res,
                 float* __restrict__ out, int relu_mode) {
    constexpr int HD = H * D;
    constexpr int SLOTS = (HD + 63) / 64;
    const int n = blockIdx.x;
    const int lane = threadIdx.x;
    const int beg = rowptr[n], end = rowptr[n + 1];

    float erh[H];
    #pragma unroll
    for (int h = 0; h < H; ++h) erh[h] = er[n * H + h];

    float m[H];
    #pragma unroll
    for (int h = 0; h < H; ++h) m[h] = -1e30f;
    for (int j = beg + lane; j < end; j += 64) {
        int s = csr_src[j];
        #pragma unroll
        for (int h = 0; h < H; ++h) {
            float x = el[s * H + h] + erh[h];
            x = (x > 0.0f) ? x : (NEGS * x);
            m[h] = fmaxf(m[h], x);
        }
    }
    #pragma unroll
    for (int h = 0; h < H; ++h)
        for (int off = 32; off; off >>= 1) m[h] = fmaxf(m[h], __shfl_xor(m[h], off, 64));

    float ssum[H];
    #pragma unroll
    for (int h = 0; h < H; ++h) ssum[h] = 0.0f;
    for (int j = beg + lane; j < end; j += 64) {
        int s = csr_src[j];
        #pragma unroll
        for (int h = 0; h < H; ++h) {
            float x = el[s * H + h] + erh[h];
            x = (x > 0.0f) ? x : (NEGS * x);
            ssum[h] += __expf(x - m[h]);
        }
    }
    #pragma unroll
    for (int h = 0; h < H; ++h) {
        for (int off = 32; off; off >>= 1) ssum[h] += __shfl_xor(ssum[h], off, 64);
        ssum[h] = (ssum[h] > 0.0f) ? 1.0f / ssum[h] : 0.0f;
    }

    __shared__ float s_alpha[64 * H];
    __shared__ int   s_src[64];
    float acc[SLOTS];
    #pragma unroll
    for (int r = 0; r < SLOTS; ++r) acc[r] = 0.0f;

    for (int chunk = beg; chunk < end; chunk += 64) {
        int j = chunk + lane;
        if (j < end) {
            int s = csr_src[j];
            s_src[lane] = s;
            #pragma unroll
            for (int h = 0; h < H; ++h) {
                float x = el[s * H + h] + erh[h];
                x = (x > 0.0f) ? x : (NEGS * x);
                s_alpha[lane * H + h] = __expf(x - m[h]) * ssum[h];
            }
        }
        __syncthreads();
        int cnt = min(64, end - chunk);
        for (int t = 0; t < cnt; ++t) {
            const float* fr = feat + (size_t)s_src[t] * HD;
            #pragma unroll
            for (int r = 0; r < SLOTS; ++r) {
                int hd = r * 64 + lane;
                if (hd < HD)
                    acc[r] += s_alpha[t * H + hd / D] * fr[hd];
            }
        }
        __syncthreads();
    }

    #pragma unroll
    for (int r = 0; r < SLOTS; ++r) {
        int hd = r * 64 + lane;
        if (hd < HD) {
            float v = acc[r];
            if (relu_mode == 2) v += res[(size_t)n * HD + hd];
            if (relu_mode) v = fmaxf(v, 0.0f);
            out[(size_t)n * HD + hd] = v;
        }
    }
}

// ---------------- residual: res = norm_dst * sum_in(rawn[src]) ----------------
__global__ void k_res_gather(const int* __restrict__ rowptr, const int* __restrict__ csr_src,
                             const float* __restrict__ rawn, const float* __restrict__ norm,
                             float* __restrict__ res, int N, int M) {
    int i = blockIdx.x * blockDim.x + threadIdx.x;
    if (i >= N * M) return;
    int n = i / M, hd = i - n * M;
    int beg = rowptr[n], end = rowptr[n + 1];
    float acc = 0.0f;
    for (int j = beg; j < end; ++j)
        acc += rawn[(size_t)csr_src[j] * M + hd];
    res[i] = acc * norm[n];
}

// ---------------- launch ----------------
extern "C" void kernel_launch(void* const* d_in, const int* in_sizes, int n_in,
                              void* d_out, int out_size, void* d_ws, size_t ws_size,
                              hipStream_t stream) {
    const float* features = (const float*)d_in[0];
    const int*   src      = (const int*)d_in[1];
    const int*   dst      = (const int*)d_in[2];
    const float* W0   = (const float*)d_in[3];
    const float* al0  = (const float*)d_in[4];
    const float* ar0  = (const float*)d_in[5];
    const float* W1   = (const float*)d_in[6];
    const float* al1  = (const float*)d_in[7];
    const float* ar1  = (const float*)d_in[8];
    const float* W2   = (const float*)d_in[9];
    const float* al2  = (const float*)d_in[10];
    const float* ar2  = (const float*)d_in[11];
    const float* Wout = (const float*)d_in[12];
    const float* alout= (const float*)d_in[13];
    const float* arout= (const float*)d_in[14];
    const float* Wraw = (const float*)d_in[15];
    const float* braw = (const float*)d_in[16];

    const int IN = 300, H = 5, D = 32, HD = 160, OUT = 10;
    const int N = in_sizes[0] / IN;   // 50000
    const int E = in_sizes[1];        // 800000

    char* w = (char*)d_ws;
    auto take = [&](size_t bytes) { char* r = w; w += (bytes + 255) & ~size_t(255); return r; };
    int*   deg     = (int*)  take((size_t)N * 4);
    int*   cnt     = (int*)  take((size_t)N * 4);
    int*   rowptr  = (int*)  take((size_t)(N + 1) * 4);
    int*   csr_src = (int*)  take((size_t)E * 4);
    float* norm    = (float*)take((size_t)N * 4);
    float* res     = (float*)take((size_t)N * HD * 4);
    float* rawn    = (float*)take((size_t)N * HD * 4);
    float* hbuf    = (float*)take((size_t)N * HD * 4);
    float* feat    = (float*)take((size_t)N * HD * 4);
    float* el      = (float*)take((size_t)N * H * 4);
    float* er      = (float*)take((size_t)N * H * 4);
    float* out = (float*)d_out;

    auto cdiv = [](long long a, long long b) { return (int)((a + b - 1) / b); };

    // 1. CSR build + norm
    hipMemsetAsync(deg, 0, (size_t)N * 4, stream);
    hipMemsetAsync(cnt, 0, (size_t)N * 4, stream);
    k_degi<<<cdiv(E, 256), 256, 0, stream>>>(dst, deg, E);
    k_scan<<<1, 1024, 0, stream>>>(deg, rowptr, norm, N);
    k_fill<<<cdiv(E, 256), 256, 0, stream>>>(src, dst, rowptr, cnt, csr_src, E);

    // 2. rawn = (features @ Wraw + braw) * norm   (norm folded into epilogue)
    k_gemm160<<<cdiv(N, 32), 256, 0, stream>>>(features, Wraw, braw, norm, rawn, N, IN);

    // 3. res = norm * gather_sum(rawn[src])   (loop-invariant)
    k_res_gather<<<cdiv((long long)N * HD, 256), 256, 0, stream>>>(rowptr, csr_src, rawn, norm, res, N, HD);

    // 4. three GAT layers
    const float* x = features; int K = IN;
    const float* Ws[3]  = {W0, W1, W2};
    const float* als[3] = {al0, al1, al2};
    const float* ars[3] = {ar0, ar1, ar2};
    for (int L = 0; L < 3; L++) {
        k_gemm160<<<cdiv(N, 32), 256, 0, stream>>>(x, Ws[L], nullptr, nullptr, feat, N, K);
        k_elr32<<<cdiv((long long)N * H, 256), 256, 0, stream>>>(feat, als[L], ars[L], el, er, N, H);
        k_gat_fused<5, 32><<<N, 64, 0, stream>>>(rowptr, csr_src, el, er, feat, res, hbuf,
                                                 (L == 0) ? 1 : 2);
        x = hbuf; K = HD;
    }

    // 5. output GAT (H=1, D=OUT); mean over 1 head == identity
    k_gemv10<<<cdiv(N, 256), 256, 0, stream>>>(hbuf, Wout, feat, N, HD);
    k_elr_gen<<<cdiv(N, 256), 256, 0, stream>>>(feat, alout, arout, el, er, N, 1, OUT);
    k_gat_fused<1, 10><<<N, 64, 0, stream>>>(rowptr, csr_src, el, er, feat, nullptr, out, 0);
}

// Round 6
// 1142.136 us; speedup vs baseline: 2.8406x; 1.2746x over previous
//
#include <hip/hip_runtime.h>
#include <hip/hip_bf16.h>

#define NEGS 0.2f

// ---------------- CSR build ----------------
__global__ void k_degi(const int* __restrict__ dst, int* __restrict__ deg, int E) {
    int e = blockIdx.x * blockDim.x + threadIdx.x;
    if (e < E) atomicAdd(&deg[dst[e]], 1);
}

__global__ __launch_bounds__(1024)
void k_scan(const int* __restrict__ deg, int* __restrict__ rowptr,
            float* __restrict__ norm, int N) {
    __shared__ int ssum[1024];
    int t = threadIdx.x;
    int chunk = (N + 1023) >> 10;
    int b = min(t * chunk, N), e = min(b + chunk, N);
    int s = 0;
    for (int i = b; i < e; ++i) s += deg[i];
    ssum[t] = s;
    __syncthreads();
    for (int off = 1; off < 1024; off <<= 1) {
        int v = (t >= off) ? ssum[t - off] : 0;
        __syncthreads();
        ssum[t] += v;
        __syncthreads();
    }
    int run = (t == 0) ? 0 : ssum[t - 1];
    for (int i = b; i < e; ++i) { rowptr[i] = run; run += deg[i]; }
    if (t == 0) rowptr[N] = ssum[1023];
    for (int i = b; i < e; ++i) norm[i] = rsqrtf(fmaxf((float)deg[i], 1.0f));
}

__global__ void k_fill(const int* __restrict__ src, const int* __restrict__ dst,
                       const int* __restrict__ rowptr, int* __restrict__ cnt,
                       int* __restrict__ csr_src, int E) {
    int e = blockIdx.x * blockDim.x + threadIdx.x;
    if (e >= E) return;
    int d = dst[e];
    int pos = rowptr[d] + atomicAdd(&cnt[d], 1);
    csr_src[pos] = src[e];
}

// ---------------- GEMM: C[N,160] = A[N,K] @ B[K,160] -----------------
__global__ __launch_bounds__(256)
void k_gemm160(const float* __restrict__ A, const float* __restrict__ B,
               const float* __restrict__ bias, const float* __restrict__ rowscale,
               float* __restrict__ C, int Nrows, int K) {
    constexpr int M = 160;
    __shared__ __align__(16) float As[2][16][36];
    __shared__ __align__(16) float Bs[2][16][160];
    const int tid = threadIdx.x;
    const int tx = tid & 31, ty = tid >> 5;
    const int r0 = blockIdx.x * 32;
    const int nT = (K + 15) / 16;

    float4 a_reg;
    float4 b_reg[3];

    auto loadA = [&](int t) {
        a_reg = make_float4(0.f, 0.f, 0.f, 0.f);
        if (tid < 128) {
            int r = tid >> 2, kq = (tid & 3) * 4;
            int row = r0 + r, kb = t * 16 + kq;
            if (row < Nrows) {
                if (kb + 3 < K) {
                    a_reg = *reinterpret_cast<const float4*>(&A[(size_t)row * K + kb]);
                } else {
                    float tmp[4] = {0.f, 0.f, 0.f, 0.f};
                    #pragma unroll
                    for (int j = 0; j < 4; ++j)
                        if (kb + j < K) tmp[j] = A[(size_t)row * K + kb + j];
                    a_reg = make_float4(tmp[0], tmp[1], tmp[2], tmp[3]);
                }
            }
        }
    };
    auto loadB = [&](int t) {
        #pragma unroll
        for (int q = 0; q < 3; ++q) {
            b_reg[q] = make_float4(0.f, 0.f, 0.f, 0.f);
            int i = tid + q * 256;
            if (i < 640) {
                int kk = i / 40, c4 = (i % 40) * 4;
                int kb = t * 16 + kk;
                if (kb < K) b_reg[q] = *reinterpret_cast<const float4*>(&B[(size_t)kb * M + c4]);
            }
        }
    };
    auto storeA = [&](int buf) {
        if (tid < 128) {
            int r = tid >> 2, kq = (tid & 3) * 4;
            As[buf][kq + 0][r] = a_reg.x; As[buf][kq + 1][r] = a_reg.y;
            As[buf][kq + 2][r] = a_reg.z; As[buf][kq + 3][r] = a_reg.w;
        }
    };
    auto storeB = [&](int buf) {
        #pragma unroll
        for (int q = 0; q < 3; ++q) {
            int i = tid + q * 256;
            if (i < 640) {
                int kk = i / 40, c4 = (i % 40) * 4;
                *reinterpret_cast<float4*>(&Bs[buf][kk][c4]) = b_reg[q];
            }
        }
    };

    float acc[4][5] = {};
    loadA(0); loadB(0);
    storeA(0); storeB(0);
    __syncthreads();
    for (int t = 0; t < nT; ++t) {
        int cur = t & 1;
        if (t + 1 < nT) { loadA(t + 1); loadB(t + 1); }
        #pragma unroll
        for (int kk = 0; kk < 16; ++kk) {
            float4 av = *reinterpret_cast<const float4*>(&As[cur][kk][ty * 4]);
            float a4[4] = {av.x, av.y, av.z, av.w};
            float bv[5];
            #pragma unroll
            for (int c = 0; c < 5; ++c) bv[c] = Bs[cur][kk][tx + 32 * c];
            #pragma unroll
            for (int r = 0; r < 4; ++r)
                #pragma unroll
                for (int c = 0; c < 5; ++c) acc[r][c] += a4[r] * bv[c];
        }
        if (t + 1 < nT) { storeA(cur ^ 1); storeB(cur ^ 1); }
        __syncthreads();
    }
    #pragma unroll
    for (int r = 0; r < 4; ++r) {
        int row = r0 + ty * 4 + r;
        if (row >= Nrows) continue;
        float sc = rowscale ? rowscale[row] : 1.0f;
        #pragma unroll
        for (int c = 0; c < 5; ++c) {
            int col = tx + 32 * c;
            float v = acc[r][c];
            if (bias) v += bias[col];
            C[(size_t)row * M + col] = v * sc;
        }
    }
}

// ---------------- small GEMM for Wout ----------------
__global__ __launch_bounds__(256)
void k_gemv10(const float* __restrict__ A, const float* __restrict__ B,
              float* __restrict__ C, int Nrows, int K) {
    __shared__ float Bs[160 * 10];
    for (int i = threadIdx.x; i < K * 10; i += 256) Bs[i] = B[i];
    __syncthreads();
    int row = blockIdx.x * 256 + threadIdx.x;
    if (row >= Nrows) return;
    float acc[10] = {};
    const float4* a = reinterpret_cast<const float4*>(A + (size_t)row * K);
    for (int kq = 0; kq < K / 4; ++kq) {
        float4 v = a[kq];
        int k = kq * 4;
        #pragma unroll
        for (int j = 0; j < 10; ++j)
            acc[j] += v.x * Bs[(k + 0) * 10 + j] + v.y * Bs[(k + 1) * 10 + j]
                    + v.z * Bs[(k + 2) * 10 + j] + v.w * Bs[(k + 3) * 10 + j];
    }
    #pragma unroll
    for (int j = 0; j < 10; ++j) C[(size_t)row * 10 + j] = acc[j];
}

// ---------------- attention logits el/er ----------------
__global__ void k_elr32(const float* __restrict__ feat, const float* __restrict__ al,
                        const float* __restrict__ ar, float* __restrict__ el,
                        float* __restrict__ er, int N, int H) {
    int i = blockIdx.x * blockDim.x + threadIdx.x;
    if (i >= N * H) return;
    int h = i % H;
    const float4* f = (const float4*)(feat + (size_t)i * 32);
    const float4* a = (const float4*)(al + h * 32);
    const float4* b = (const float4*)(ar + h * 32);
    float sl = 0.0f, sr = 0.0f;
    #pragma unroll
    for (int d = 0; d < 8; d++) {
        float4 v = f[d], x = a[d], y = b[d];
        sl += v.x * x.x + v.y * x.y + v.z * x.z + v.w * x.w;
        sr += v.x * y.x + v.y * y.y + v.z * y.z + v.w * y.w;
    }
    el[i] = sl; er[i] = sr;
}

__global__ void k_elr_gen(const float* __restrict__ feat, const float* __restrict__ al,
                          const float* __restrict__ ar, float* __restrict__ el,
                          float* __restrict__ er, int N, int H, int D) {
    int i = blockIdx.x * blockDim.x + threadIdx.x;
    if (i >= N * H) return;
    int h = i % H;
    const float* f = feat + (size_t)i * D;
    const float* a = al + h * D;
    const float* b = ar + h * D;
    float sl = 0.0f, sr = 0.0f;
    for (int d = 0; d < D; d++) { float v = f[d]; sl += v * a[d]; sr += v * b[d]; }
    el[i] = sl; er[i] = sr;
}

// ---------------- fused GAT v2: online softmax + float4 weighted gather ----
// One wave per dst node. relu_mode: 0 none, 1 relu, 2 add res then relu.
template<int H, int D>
__global__ __launch_bounds__(64)
void k_gat_fused(const int* __restrict__ rowptr, const int* __restrict__ csr_src,
                 const float* __restrict__ el, const float* __restrict__ er,
                 const float* __restrict__ feat, const float* __restrict__ res,
                 float* __restrict__ out, int relu_mode) {
    constexpr int HD = H * D;
    const int n = blockIdx.x;
    const int lane = threadIdx.x;
    const int beg = rowptr[n], end = rowptr[n + 1];

    float erh[H];
    #pragma unroll
    for (int h = 0; h < H; ++h) erh[h] = er[n * H + h];

    // pass A: single-pass online softmax stats (max m, rescaled sum ssum)
    float m[H], ssum[H];
    #pragma unroll
    for (int h = 0; h < H; ++h) { m[h] = -1e30f; ssum[h] = 0.0f; }
    for (int j = beg + lane; j < end; j += 64) {
        int s = csr_src[j];
        #pragma unroll
        for (int h = 0; h < H; ++h) {
            float x = el[s * H + h] + erh[h];
            x = (x > 0.0f) ? x : (NEGS * x);
            float mn = fmaxf(m[h], x);
            ssum[h] = ssum[h] * __expf(m[h] - mn) + __expf(x - mn);
            m[h] = mn;
        }
    }
    float inv[H];
    #pragma unroll
    for (int h = 0; h < H; ++h) {
        #pragma unroll
        for (int off = 32; off; off >>= 1) {
            float mo = __shfl_xor(m[h], off, 64);
            float so = __shfl_xor(ssum[h], off, 64);
            float mn = fmaxf(m[h], mo);
            ssum[h] = ssum[h] * __expf(m[h] - mn) + so * __expf(mo - mn);
            m[h] = mn;
        }
        inv[h] = (ssum[h] > 0.0f) ? 1.0f / ssum[h] : 0.0f;
    }

    // pass B: weighted gather-accumulate
    __shared__ float s_alpha[64 * H];
    __shared__ int   s_src[64];

    if constexpr ((D & 3) == 0) {
        constexpr int NV = HD / 4;           // active lanes, 16B each
        const int hc = (lane * 4) / D;       // head of this lane's 4 elems
        float4 acc = make_float4(0.f, 0.f, 0.f, 0.f);
        for (int chunk = beg; chunk < end; chunk += 64) {
            int j = chunk + lane;
            if (j < end) {
                int s = csr_src[j];
                s_src[lane] = s;
                #pragma unroll
                for (int h = 0; h < H; ++h) {
                    float x = el[s * H + h] + erh[h];
                    x = (x > 0.0f) ? x : (NEGS * x);
                    s_alpha[lane * H + h] = __expf(x - m[h]) * inv[h];
                }
            }
            __syncthreads();
            int cnt = min(64, end - chunk);
            if (lane < NV) {
                for (int t = 0; t < cnt; ++t) {
                    const float4 v = *reinterpret_cast<const float4*>(
                        feat + (size_t)s_src[t] * HD + lane * 4);
                    float a = s_alpha[t * H + hc];
                    acc.x += a * v.x; acc.y += a * v.y;
                    acc.z += a * v.z; acc.w += a * v.w;
                }
            }
            __syncthreads();
        }
        if (lane < NV) {
            float4 v = acc;
            if (relu_mode == 2) {
                const float4 rv = *reinterpret_cast<const float4*>(
                    res + (size_t)n * HD + lane * 4);
                v.x += rv.x; v.y += rv.y; v.z += rv.z; v.w += rv.w;
            }
            if (relu_mode) {
                v.x = fmaxf(v.x, 0.f); v.y = fmaxf(v.y, 0.f);
                v.z = fmaxf(v.z, 0.f); v.w = fmaxf(v.w, 0.f);
            }
            *reinterpret_cast<float4*>(out + (size_t)n * HD + lane * 4) = v;
        }
    } else {
        constexpr int SLOTS = (HD + 63) / 64;
        float acc[SLOTS];
        #pragma unroll
        for (int r = 0; r < SLOTS; ++r) acc[r] = 0.0f;
        for (int chunk = beg; chunk < end; chunk += 64) {
            int j = chunk + lane;
            if (j < end) {
                int s = csr_src[j];
                s_src[lane] = s;
                #pragma unroll
                for (int h = 0; h < H; ++h) {
                    float x = el[s * H + h] + erh[h];
                    x = (x > 0.0f) ? x : (NEGS * x);
                    s_alpha[lane * H + h] = __expf(x - m[h]) * inv[h];
                }
            }
            __syncthreads();
            int cnt = min(64, end - chunk);
            for (int t = 0; t < cnt; ++t) {
                const float* fr = feat + (size_t)s_src[t] * HD;
                #pragma unroll
                for (int r = 0; r < SLOTS; ++r) {
                    int hd = r * 64 + lane;
                    if (hd < HD)
                        acc[r] += s_alpha[t * H + hd / D] * fr[hd];
                }
            }
            __syncthreads();
        }
        #pragma unroll
        for (int r = 0; r < SLOTS; ++r) {
            int hd = r * 64 + lane;
            if (hd < HD) {
                float v = acc[r];
                if (relu_mode == 2) v += res[(size_t)n * HD + hd];
                if (relu_mode) v = fmaxf(v, 0.0f);
                out[(size_t)n * HD + hd] = v;
            }
        }
    }
}

// ---------------- residual: res = norm_dst * sum_in(rawn[src]), float4 ----
__global__ void k_res_gather4(const int* __restrict__ rowptr, const int* __restrict__ csr_src,
                              const float* __restrict__ rawn, const float* __restrict__ norm,
                              float* __restrict__ res, int N) {
    constexpr int M4 = 40;   // 160/4
    int i = blockIdx.x * blockDim.x + threadIdx.x;
    if (i >= N * M4) return;
    int n = i / M4, q = i - n * M4;
    int beg = rowptr[n], end = rowptr[n + 1];
    float4 acc = make_float4(0.f, 0.f, 0.f, 0.f);
    for (int j = beg; j < end; ++j) {
        const float4 v = *reinterpret_cast<const float4*>(
            rawn + (size_t)csr_src[j] * 160 + q * 4);
        acc.x += v.x; acc.y += v.y; acc.z += v.z; acc.w += v.w;
    }
    float sc = norm[n];
    acc.x *= sc; acc.y *= sc; acc.z *= sc; acc.w *= sc;
    *reinterpret_cast<float4*>(res + (size_t)n * 160 + q * 4) = acc;
}

// ---------------- launch ----------------
extern "C" void kernel_launch(void* const* d_in, const int* in_sizes, int n_in,
                              void* d_out, int out_size, void* d_ws, size_t ws_size,
                              hipStream_t stream) {
    const float* features = (const float*)d_in[0];
    const int*   src      = (const int*)d_in[1];
    const int*   dst      = (const int*)d_in[2];
    const float* W0   = (const float*)d_in[3];
    const float* al0  = (const float*)d_in[4];
    const float* ar0  = (const float*)d_in[5];
    const float* W1   = (const float*)d_in[6];
    const float* al1  = (const float*)d_in[7];
    const float* ar1  = (const float*)d_in[8];
    const float* W2   = (const float*)d_in[9];
    const float* al2  = (const float*)d_in[10];
    const float* ar2  = (const float*)d_in[11];
    const float* Wout = (const float*)d_in[12];
    const float* alout= (const float*)d_in[13];
    const float* arout= (const float*)d_in[14];
    const float* Wraw = (const float*)d_in[15];
    const float* braw = (const float*)d_in[16];

    const int IN = 300, H = 5, D = 32, HD = 160, OUT = 10;
    const int N = in_sizes[0] / IN;   // 50000
    const int E = in_sizes[1];        // 800000

    char* w = (char*)d_ws;
    auto take = [&](size_t bytes) { char* r = w; w += (bytes + 255) & ~size_t(255); return r; };
    int*   deg     = (int*)  take((size_t)N * 4);
    int*   cnt     = (int*)  take((size_t)N * 4);
    int*   rowptr  = (int*)  take((size_t)(N + 1) * 4);
    int*   csr_src = (int*)  take((size_t)E * 4);
    float* norm    = (float*)take((size_t)N * 4);
    float* res     = (float*)take((size_t)N * HD * 4);
    float* rawn    = (float*)take((size_t)N * HD * 4);
    float* hbuf    = (float*)take((size_t)N * HD * 4);
    float* feat    = (float*)take((size_t)N * HD * 4);
    float* el      = (float*)take((size_t)N * H * 4);
    float* er      = (float*)take((size_t)N * H * 4);
    float* out = (float*)d_out;

    auto cdiv = [](long long a, long long b) { return (int)((a + b - 1) / b); };

    // 1. CSR build + norm
    hipMemsetAsync(deg, 0, (size_t)N * 4, stream);
    hipMemsetAsync(cnt, 0, (size_t)N * 4, stream);
    k_degi<<<cdiv(E, 256), 256, 0, stream>>>(dst, deg, E);
    k_scan<<<1, 1024, 0, stream>>>(deg, rowptr, norm, N);
    k_fill<<<cdiv(E, 256), 256, 0, stream>>>(src, dst, rowptr, cnt, csr_src, E);

    // 2. rawn = (features @ Wraw + braw) * norm
    k_gemm160<<<cdiv(N, 32), 256, 0, stream>>>(features, Wraw, braw, norm, rawn, N, IN);

    // 3. res = norm * gather_sum(rawn[src])
    k_res_gather4<<<cdiv((long long)N * 40, 256), 256, 0, stream>>>(rowptr, csr_src, rawn, norm, res, N);

    // 4. three GAT layers
    const float* x = features; int K = IN;
    const float* Ws[3]  = {W0, W1, W2};
    const float* als[3] = {al0, al1, al2};
    const float* ars[3] = {ar0, ar1, ar2};
    for (int L = 0; L < 3; L++) {
        k_gemm160<<<cdiv(N, 32), 256, 0, stream>>>(x, Ws[L], nullptr, nullptr, feat, N, K);
        k_elr32<<<cdiv((long long)N * H, 256), 256, 0, stream>>>(feat, als[L], ars[L], el, er, N, H);
        k_gat_fused<5, 32><<<N, 64, 0, stream>>>(rowptr, csr_src, el, er, feat, res, hbuf,
                                                 (L == 0) ? 1 : 2);
        x = hbuf; K = HD;
    }

    // 5. output GAT (H=1, D=OUT); mean over 1 head == identity
    k_gemv10<<<cdiv(N, 256), 256, 0, stream>>>(hbuf, Wout, feat, N, HD);
    k_elr_gen<<<cdiv(N, 256), 256, 0, stream>>>(feat, alout, arout, el, er, N, 1, OUT);
    k_gat_fused<1, 10><<<N, 64, 0, stream>>>(rowptr, csr_src, el, er, feat, nullptr, out, 0);
}